// Round 5
// baseline (2179.820 us; speedup 1.0000x reference)
//
#include <hip/hip_runtime.h>
#include <math.h>

typedef unsigned short ushortT;
typedef __attribute__((ext_vector_type(8))) short short8;
typedef __attribute__((ext_vector_type(4))) float f32x4;

#define NN 4096
#define DD 1024
#define NC 100
#define CP 128
#define NLAB 2048
#define NITER 30

__device__ __forceinline__ ushortT bf16rn(float x) {
  unsigned u = __float_as_uint(x);
  unsigned r = (u + 0x7fffu + ((u >> 16) & 1u)) >> 16;
  return (ushortT)r;
}
__device__ __forceinline__ float bf2f(ushortT h) {
  return __uint_as_float(((unsigned)h) << 16);
}
__device__ __forceinline__ void gload16(const void* g, void* l) {
  __builtin_amdgcn_global_load_lds((const __attribute__((address_space(1))) char*)g,
                                   (__attribute__((address_space(3))) char*)l, 16, 0, 0);
}

// ---------------- normalize rows -> bf16 hi/lo splits ----------------
__global__ __launch_bounds__(256) void k_normalize(const float* __restrict__ E,
                                                   ushortT* __restrict__ Enh,
                                                   ushortT* __restrict__ Enl) {
  int row = blockIdx.x, t = threadIdx.x;
  const float4* e4 = (const float4*)(E + (size_t)row * DD);
  float4 v = e4[t];
  float ss = v.x * v.x + v.y * v.y + v.z * v.z + v.w * v.w;
  __shared__ float red[4];
  int lane = t & 63, w = t >> 6;
#pragma unroll
  for (int off = 32; off; off >>= 1) ss += __shfl_xor(ss, off);
  if (lane == 0) red[w] = ss;
  __syncthreads();
  float tot = red[0] + red[1] + red[2] + red[3];
  float d = fmaxf(sqrtf(tot), 1e-12f);
  float xs[4] = {v.x / d, v.y / d, v.z / d, v.w / d};
  ushort4 hv, lv;
  ushortT h;
  h = bf16rn(xs[0]); hv.x = h; lv.x = bf16rn(xs[0] - bf2f(h));
  h = bf16rn(xs[1]); hv.y = h; lv.y = bf16rn(xs[1] - bf2f(h));
  h = bf16rn(xs[2]); hv.z = h; lv.z = bf16rn(xs[2] - bf2f(h));
  h = bf16rn(xs[3]); hv.w = h; lv.w = bf16rn(xs[3] - bf2f(h));
  ((ushort4*)Enh)[(size_t)row * 256 + t] = hv;
  ((ushort4*)Enl)[(size_t)row * 256 + t] = lv;
}

// ---------------- A0 = relu(En@En^T) via MFMA, 3-term bf16 split; diag=1 ----------------
// Upper-tri block grid (528); mirror via LDS transpose -> coalesced stores.
__global__ __launch_bounds__(256) void k_syrk_mfma(const ushortT* __restrict__ Enh,
                                                   const ushortT* __restrict__ Enl,
                                                   float* __restrict__ A) {
  __shared__ ushortT lds[2][16384];  // per buf: A-tile [128][64] @0, B-tile @8192
  int t = threadIdx.x;
  int l = t & 63, w = t >> 6;
  int rem = blockIdx.x, bi = 0;
  while (rem >= (32 - bi)) { rem -= (32 - bi); ++bi; }
  int bj = bi + rem;
  int i0 = bi << 7, j0 = bj << 7;
  int wr = w >> 1, wc = w & 1;
  f32x4 zz = {0.f, 0.f, 0.f, 0.f};
  f32x4 acc[4][4];
#pragma unroll
  for (int m = 0; m < 4; ++m)
#pragma unroll
    for (int n = 0; n < 4; ++n) acc[m][n] = zz;
  int arow_l = l & 15, kslot = l >> 4;

  auto stage = [&](int b, int s) {
    int term = s >> 4;
    int kk0 = (s & 15) << 6;
    const ushortT* sa = (term == 2) ? Enl : Enh;
    const ushortT* sb = (term == 1) ? Enl : Enh;
#pragma unroll
    for (int q = 0; q < 4; ++q) {
      int n = (q << 8) + t;
      int r = n >> 3, p = n & 7;
      int col = (p ^ (r & 7)) << 3;
      gload16(sa + (size_t)(i0 + r) * DD + kk0 + col, &lds[b][n << 3]);
      gload16(sb + (size_t)(j0 + r) * DD + kk0 + col, &lds[b][8192 + (n << 3)]);
    }
  };

  stage(0, 0);
  int cur = 0;
  for (int s = 0; s < 48; ++s) {
    if (s < 47) {
      stage(cur ^ 1, s + 1);
      asm volatile("s_waitcnt vmcnt(8)" ::: "memory");
    } else {
      asm volatile("s_waitcnt vmcnt(0)" ::: "memory");
    }
    __builtin_amdgcn_s_barrier();
#pragma unroll
    for (int kk = 0; kk < 2; ++kk) {
      int g = (kk << 2) + kslot;
      short8 av[4], bv[4];
#pragma unroll
      for (int m = 0; m < 4; ++m) {
        int r = (wr << 6) + (m << 4) + arow_l;
        av[m] = *(const short8*)&lds[cur][(r << 6) + ((g ^ (r & 7)) << 3)];
      }
#pragma unroll
      for (int n = 0; n < 4; ++n) {
        int r = (wc << 6) + (n << 4) + arow_l;
        bv[n] = *(const short8*)&lds[cur][8192 + (r << 6) + ((g ^ (r & 7)) << 3)];
      }
#pragma unroll
      for (int m = 0; m < 4; ++m)
#pragma unroll
        for (int n = 0; n < 4; ++n)
          acc[m][n] = __builtin_amdgcn_mfma_f32_16x16x32_bf16(av[m], bv[n], acc[m][n], 0, 0, 0);
    }
    asm volatile("s_waitcnt lgkmcnt(0)" ::: "memory");
    __builtin_amdgcn_s_barrier();
    cur ^= 1;
  }
  int rbase = (l >> 4) << 2;
  // direct store of own tile (coalesced over gj)
#pragma unroll
  for (int m = 0; m < 4; ++m) {
#pragma unroll
    for (int n = 0; n < 4; ++n) {
#pragma unroll
      for (int r = 0; r < 4; ++r) {
        int gi = i0 + (wr << 6) + (m << 4) + rbase + r;
        int gj = j0 + (wc << 6) + (n << 4) + (l & 15);
        float v = fmaxf(acc[m][n][r], 0.0f);
        if (gi == gj) v = 1.0f;
        A[(size_t)gi * NN + gj] = v;
      }
    }
  }
  // mirror via LDS transpose: two chunks of T[128 local_j][68 pad] covering local_i halves
  if (bi != bj) {
    float* T = (float*)&lds[0][0];  // 128*68*4 = 34816 B <= 64 KB
#pragma unroll
    for (int c2 = 0; c2 < 2; ++c2) {
      __syncthreads();
      if (wr == c2) {
#pragma unroll
        for (int m = 0; m < 4; ++m)
#pragma unroll
          for (int n = 0; n < 4; ++n)
#pragma unroll
            for (int r = 0; r < 4; ++r)
              T[(((wc << 6) + (n << 4) + (l & 15)) * 68) + (m << 4) + rbase + r] =
                  fmaxf(acc[m][n][r], 0.0f);
      }
      __syncthreads();
      int lj = t >> 1, cg = (t & 1) << 5;
#pragma unroll
      for (int q = 0; q < 8; ++q) {
        float4 vq = *(const float4*)&T[lj * 68 + cg + (q << 2)];
        *(float4*)&A[(size_t)(j0 + lj) * NN + i0 + (c2 << 6) + cg + (q << 2)] = vq;
      }
    }
  }
}

// ---------------- sigma[i] = 7th largest of row i (float4 loads) ----------------
__device__ __forceinline__ void ins7(float (&tv)[7], float v) {
  if (v > tv[6]) {
#pragma unroll
    for (int s = 0; s < 7; s++) {
      if (v > tv[s]) { float tmp = tv[s]; tv[s] = v; v = tmp; }
    }
  }
}
__global__ __launch_bounds__(256) void k_top7(const float* __restrict__ A,
                                              float* __restrict__ sig) {
  int w = threadIdx.x >> 6, lane = threadIdx.x & 63;
  int row = (blockIdx.x << 2) + w;
  const float4* a4 = (const float4*)(A + (size_t)row * NN);
  float tv[7];
#pragma unroll
  for (int i = 0; i < 7; i++) tv[i] = -1.0f;
  for (int k = 0; k < 16; k++) {
    float4 v = a4[(k << 6) + lane];
    ins7(tv, v.x); ins7(tv, v.y); ins7(tv, v.z); ins7(tv, v.w);
  }
  int head = 0;
  float seventh = 0.0f;
  for (int r = 0; r < 7; r++) {
    float h = (head < 7) ? tv[head] : -1.0f;
    float m = h;
#pragma unroll
    for (int off = 32; off; off >>= 1) m = fmaxf(m, __shfl_xor(m, off));
    unsigned long long ball = __ballot(h == m);
    if (lane == (__ffsll(ball) - 1)) head++;
    seventh = m;
  }
  if (lane == 0) sig[row] = seventh;
}

// ---------------- transform all rows for mean; store only bottom half ----------------
__global__ __launch_bounds__(256) void k_transform(float* __restrict__ A,
                                                   const float* __restrict__ sig,
                                                   double* __restrict__ parts) {
  int row = blockIdx.x;
  float si = sig[row];
  float4* a4 = (float4*)(A + (size_t)row * NN);
  const float4* s4 = (const float4*)sig;
  int t = threadIdx.x;
  bool store = (row >= NLAB);
  double local = 0.0;
#pragma unroll
  for (int k = 0; k < 4; k++) {
    int j = (k << 8) + t;
    float4 v = a4[j];
    float4 sg = s4[j];
    float4 ww;
    ww.x = expf(-(v.x * v.x) / (si * sg.x));
    ww.y = expf(-(v.y * v.y) / (si * sg.y));
    ww.z = expf(-(v.z * v.z) / (si * sg.z));
    ww.w = expf(-(v.w * v.w) / (si * sg.w));
    if (store) a4[j] = ww;
    local += (double)ww.x + (double)ww.y + (double)ww.z + (double)ww.w;
  }
  __shared__ double dred[4];
  int lane = t & 63, wv = t >> 6;
#pragma unroll
  for (int off = 32; off; off >>= 1) local += __shfl_xor(local, off);
  if (lane == 0) dred[wv] = local;
  __syncthreads();
  if (t == 0) parts[row] = dred[0] + dred[1] + dred[2] + dred[3];
}

__global__ __launch_bounds__(256) void k_mean(const double* __restrict__ parts,
                                              float* __restrict__ meanb) {
  int t = threadIdx.x;
  double local = 0.0;
#pragma unroll
  for (int k = 0; k < NN / 256; k++) local += parts[(k << 8) + t];
  __shared__ double dred[4];
  int lane = t & 63, wv = t >> 6;
#pragma unroll
  for (int off = 32; off; off >>= 1) local += __shfl_xor(local, off);
  if (lane == 0) dred[wv] = local;
  __syncthreads();
  if (t == 0) meanb[0] = (float)((dred[0] + dred[1] + dred[2] + dred[3]) / ((double)NN * (double)NN));
}

// ---------------- threshold bottom half + bf16 hi/lo split ----------------
__global__ __launch_bounds__(256) void k_thresh_bf(const float* __restrict__ A,
                                                   const float* __restrict__ meanb,
                                                   ushortT* __restrict__ Abh,
                                                   ushortT* __restrict__ Abl) {
  float m = meanb[0];
  size_t i4 = ((size_t)blockIdx.x << 8) + threadIdx.x;  // over 2048*4096/4
  float4 v = ((const float4*)(A + (size_t)NLAB * NN))[i4];
  float c0 = (v.x < m) ? 0.0f : v.x;
  float c1 = (v.y < m) ? 0.0f : v.y;
  float c2 = (v.z < m) ? 0.0f : v.z;
  float c3 = (v.w < m) ? 0.0f : v.w;
  ushort4 hv, lv;
  ushortT h;
  h = bf16rn(c0); hv.x = h; lv.x = bf16rn(c0 - bf2f(h));
  h = bf16rn(c1); hv.y = h; lv.y = bf16rn(c1 - bf2f(h));
  h = bf16rn(c2); hv.z = h; lv.z = bf16rn(c2 - bf2f(h));
  h = bf16rn(c3); hv.w = h; lv.w = bf16rn(c3 - bf2f(h));
  ((ushort4*)Abh)[i4] = hv;
  ((ushort4*)Abl)[i4] = lv;
}

// ---------------- one-hot labels, transposed bf16 [128][2048] ----------------
__global__ __launch_bounds__(256) void k_xlabt(const int* __restrict__ labels,
                                               ushortT* __restrict__ Xlabt) {
  int idx = (blockIdx.x << 8) + threadIdx.x;  // 262144
  int c = idx >> 11, j = idx & 2047;
  Xlabt[idx] = (labels[j] == c) ? (ushortT)0x3F80 : (ushortT)0;
}

// ---------------- fused iterations: persistent kernel, grid 128 x 512, atomic barrier ----
__global__ __launch_bounds__(512) void k_fused(
    const ushortT* __restrict__ Abh, const ushortT* __restrict__ Abl,
    const ushortT* __restrict__ Xlabt, ushortT* __restrict__ Xt0,
    ushortT* __restrict__ Xt1, float* __restrict__ Xf,
    unsigned int* __restrict__ cnt) {
  __shared__ float red[8 * 16 * 132];  // [wave][row16][col pad132] = 67.5 KB
  int t = threadIdx.x, l = t & 63, w = t >> 6;
  int brow0 = (int)blockIdx.x << 4;
  int arow = l & 15, khi = l >> 4;
  int row = t >> 5, c4 = (t & 31) << 2;
  int rb = khi << 2;

  // GEMM over K=2048 (wave K-split 256) + LDS cross-wave reduce.
  auto gemm = [&](int acol, const ushortT* __restrict__ Xt) -> float4 {
    f32x4 acc[8];
#pragma unroll
    for (int n = 0; n < 8; ++n) acc[n] = (f32x4){0.f, 0.f, 0.f, 0.f};
    const ushortT* aph = Abh + (size_t)(brow0 + arow) * NN + acol + (w << 8) + (khi << 3);
    const ushortT* apl = Abl + (size_t)(brow0 + arow) * NN + acol + (w << 8) + (khi << 3);
    const ushortT* xp = Xt + (size_t)arow * NLAB + (w << 8) + (khi << 3);
#pragma unroll
    for (int g = 0; g < 8; ++g) {
      short8 ahv = *(const short8*)(aph + (g << 5));
      short8 alv = *(const short8*)(apl + (g << 5));
#pragma unroll
      for (int n = 0; n < 8; ++n) {
        short8 bv = *(const short8*)(xp + ((size_t)(n << 4)) * NLAB + (g << 5));
        acc[n] = __builtin_amdgcn_mfma_f32_16x16x32_bf16(ahv, bv, acc[n], 0, 0, 0);
        acc[n] = __builtin_amdgcn_mfma_f32_16x16x32_bf16(alv, bv, acc[n], 0, 0, 0);
      }
    }
    __syncthreads();  // red free from previous use
#pragma unroll
    for (int n = 0; n < 8; ++n)
#pragma unroll
      for (int rr = 0; rr < 4; ++rr)
        red[((w << 4) + rb + rr) * 132 + (n << 4) + arow] = acc[n][rr];
    __syncthreads();
    float4 s = {0.f, 0.f, 0.f, 0.f};
#pragma unroll
    for (int w2 = 0; w2 < 8; ++w2) {
      float4 p = *(const float4*)&red[((w2 << 4) + row) * 132 + c4];
      s.x += p.x; s.y += p.y; s.z += p.z; s.w += p.w;
    }
    return s;
  };

  auto barrier = [&](unsigned int target) {
    __threadfence();   // release: drain + write-back so other XCDs see our X^T
    __syncthreads();
    if (t == 0) {
      atomicAdd(cnt, 1u);
      while (atomicAdd(cnt, 0u) < target) __builtin_amdgcn_s_sleep(8);
    }
    __syncthreads();
    __threadfence();   // acquire: invalidate stale cache before reading others' X^T
  };

  // ---- Ylab (constant) in registers ----
  float4 yl = gemm(0, Xlabt);

  // ---- x init + publish X^T(0) ----
  float4 x;
  x.x = (c4 + 0 < NC) ? 0.01f : 0.0f;
  x.y = (c4 + 1 < NC) ? 0.01f : 0.0f;
  x.z = (c4 + 2 < NC) ? 0.01f : 0.0f;
  x.w = (c4 + 3 < NC) ? 0.01f : 0.0f;
  int grow = brow0 + row;
  Xt0[(size_t)(c4 + 0) * NLAB + grow] = bf16rn(x.x);
  Xt0[(size_t)(c4 + 1) * NLAB + grow] = bf16rn(x.y);
  Xt0[(size_t)(c4 + 2) * NLAB + grow] = bf16rn(x.z);
  Xt0[(size_t)(c4 + 3) * NLAB + grow] = bf16rn(x.w);
  barrier(128u * 1u);

  // ---- 30 iterations ----
  for (int it = 0; it < NITER; ++it) {
    const ushortT* Xcur = (it & 1) ? Xt1 : Xt0;
    ushortT* Xnxt = (it & 1) ? Xt0 : Xt1;
    float4 mmv = gemm(NLAB, Xcur);
    float mult[4];
    mult[0] = fmaf(x.x, mmv.x + yl.x, x.x);
    mult[1] = fmaf(x.y, mmv.y + yl.y, x.y);
    mult[2] = fmaf(x.z, mmv.z + yl.z, x.z);
    mult[3] = fmaf(x.w, mmv.w + yl.w, x.w);
    float s = mult[0] + mult[1] + mult[2] + mult[3];
#pragma unroll
    for (int off = 16; off; off >>= 1) s += __shfl_xor(s, off);
    float denom = s + 1e-8f;
    x.x = mult[0] / denom; x.y = mult[1] / denom;
    x.z = mult[2] / denom; x.w = mult[3] / denom;
    if (it < NITER - 1) {
      Xnxt[(size_t)(c4 + 0) * NLAB + grow] = bf16rn(x.x);
      Xnxt[(size_t)(c4 + 1) * NLAB + grow] = bf16rn(x.y);
      Xnxt[(size_t)(c4 + 2) * NLAB + grow] = bf16rn(x.z);
      Xnxt[(size_t)(c4 + 3) * NLAB + grow] = bf16rn(x.w);
      barrier(128u * (unsigned)(it + 2));
    }
  }
  *(float4*)&Xf[(size_t)grow * CP + c4] = x;
}

// ---------------- output assembly ----------------
__global__ __launch_bounds__(256) void k_output(const float* __restrict__ Xf,
                                                const int* __restrict__ labels,
                                                float* __restrict__ out) {
  int idx = (blockIdx.x << 8) + threadIdx.x;  // 409600
  int i = idx / NC, c = idx - i * NC;
  float v;
  if (i < NLAB) v = (labels[i] == c) ? 1.0f : 0.0f;
  else v = Xf[((size_t)(i - NLAB) << 7) + c];
  out[idx] = v;
}

extern "C" void kernel_launch(void* const* d_in, const int* in_sizes, int n_in,
                              void* d_out, int out_size, void* d_ws, size_t ws_size,
                              hipStream_t stream) {
  const float* E = (const float*)d_in[0];
  const int* labels = (const int*)d_in[1];
  float* out = (float*)d_out;
  char* ws = (char*)d_ws;
  const size_t MB = 1024 * 1024;

  float* A = (float*)ws;                          // 64 MB (dead after thresh_bf)
  ushortT* Enh = (ushortT*)(ws + 64 * MB);        // 8 MB
  ushortT* Enl = (ushortT*)(ws + 72 * MB);        // 8 MB
  ushortT* Abh = (ushortT*)(ws + 80 * MB);        // 16 MB [2048][4096] bf16
  ushortT* Abl = (ushortT*)(ws + 96 * MB);        // 16 MB
  float* sig = (float*)(ws + 112 * MB);
  double* parts = (double*)(ws + 112 * MB + 65536);
  float* meanb = (float*)(ws + 112 * MB + 131072);
  ushortT* Xlabt = (ushortT*)(ws + 113 * MB);     // 0.5 MB [128][2048]
  float* Xf = (float*)(ws + 115 * MB);            // 1 MB final X
  ushortT* Xt0 = (ushortT*)(ws + 117 * MB);       // 0.5 MB X^T bf16 dbuf
  ushortT* Xt1 = (ushortT*)(ws + 118 * MB);
  unsigned int* cnt = (unsigned int*)(ws + 119 * MB);

  k_normalize<<<NN, 256, 0, stream>>>(E, Enh, Enl);
  k_syrk_mfma<<<528, 256, 0, stream>>>(Enh, Enl, A);
  k_top7<<<NN / 4, 256, 0, stream>>>(A, sig);
  k_transform<<<NN, 256, 0, stream>>>(A, sig, parts);
  k_mean<<<1, 256, 0, stream>>>(parts, meanb);
  k_thresh_bf<<<8192, 256, 0, stream>>>(A, meanb, Abh, Abl);
  k_xlabt<<<1024, 256, 0, stream>>>(labels, Xlabt);
  hipMemsetAsync(cnt, 0, sizeof(unsigned int), stream);
  k_fused<<<128, 512, 0, stream>>>(Abh, Abl, Xlabt, Xt0, Xt1, Xf, cnt);
  k_output<<<1600, 256, 0, stream>>>(Xf, labels, out);
}

// Round 6
// 759.745 us; speedup vs baseline: 2.8691x; 2.8691x over previous
//
#include <hip/hip_runtime.h>
#include <math.h>

typedef unsigned short ushortT;
typedef __attribute__((ext_vector_type(8))) short short8;
typedef __attribute__((ext_vector_type(4))) float f32x4;

#define NN 4096
#define DD 1024
#define NC 100
#define CP 128
#define NLAB 2048
#define NITER 30

__device__ __forceinline__ ushortT bf16rn(float x) {
  unsigned u = __float_as_uint(x);
  unsigned r = (u + 0x7fffu + ((u >> 16) & 1u)) >> 16;
  return (ushortT)r;
}
__device__ __forceinline__ float bf2f(ushortT h) {
  return __uint_as_float(((unsigned)h) << 16);
}
__device__ __forceinline__ void gload16(const void* g, void* l) {
  __builtin_amdgcn_global_load_lds((const __attribute__((address_space(1))) char*)g,
                                   (__attribute__((address_space(3))) char*)l, 16, 0, 0);
}

// ---------------- normalize rows -> bf16 hi/lo splits ----------------
__global__ __launch_bounds__(256) void k_normalize(const float* __restrict__ E,
                                                   ushortT* __restrict__ Enh,
                                                   ushortT* __restrict__ Enl) {
  int row = blockIdx.x, t = threadIdx.x;
  const float4* e4 = (const float4*)(E + (size_t)row * DD);
  float4 v = e4[t];
  float ss = v.x * v.x + v.y * v.y + v.z * v.z + v.w * v.w;
  __shared__ float red[4];
  int lane = t & 63, w = t >> 6;
#pragma unroll
  for (int off = 32; off; off >>= 1) ss += __shfl_xor(ss, off);
  if (lane == 0) red[w] = ss;
  __syncthreads();
  float tot = red[0] + red[1] + red[2] + red[3];
  float d = fmaxf(sqrtf(tot), 1e-12f);
  float xs[4] = {v.x / d, v.y / d, v.z / d, v.w / d};
  ushort4 hv, lv;
  ushortT h;
  h = bf16rn(xs[0]); hv.x = h; lv.x = bf16rn(xs[0] - bf2f(h));
  h = bf16rn(xs[1]); hv.y = h; lv.y = bf16rn(xs[1] - bf2f(h));
  h = bf16rn(xs[2]); hv.z = h; lv.z = bf16rn(xs[2] - bf2f(h));
  h = bf16rn(xs[3]); hv.w = h; lv.w = bf16rn(xs[3] - bf2f(h));
  ((ushort4*)Enh)[(size_t)row * 256 + t] = hv;
  ((ushort4*)Enl)[(size_t)row * 256 + t] = lv;
}

// ---------------- A0 = relu(En@En^T) via MFMA, 3-term bf16 split; diag=1 ----------------
// Upper-tri block grid (528); mirror via LDS transpose; 2 blocks/CU.
__global__ __launch_bounds__(256, 2) void k_syrk_mfma(const ushortT* __restrict__ Enh,
                                                      const ushortT* __restrict__ Enl,
                                                      float* __restrict__ A) {
  __shared__ ushortT lds[2][16384];  // per buf: A-tile [128][64] @0, B-tile @8192
  int t = threadIdx.x;
  int l = t & 63, w = t >> 6;
  int rem = blockIdx.x, bi = 0;
  while (rem >= (32 - bi)) { rem -= (32 - bi); ++bi; }
  int bj = bi + rem;
  int i0 = bi << 7, j0 = bj << 7;
  int wr = w >> 1, wc = w & 1;
  f32x4 zz = {0.f, 0.f, 0.f, 0.f};
  f32x4 acc[4][4];
#pragma unroll
  for (int m = 0; m < 4; ++m)
#pragma unroll
    for (int n = 0; n < 4; ++n) acc[m][n] = zz;
  int arow_l = l & 15, kslot = l >> 4;

  auto stage = [&](int b, int s) {
    int term = s >> 4;
    int kk0 = (s & 15) << 6;
    const ushortT* sa = (term == 2) ? Enl : Enh;
    const ushortT* sb = (term == 1) ? Enl : Enh;
#pragma unroll
    for (int q = 0; q < 4; ++q) {
      int n = (q << 8) + t;
      int r = n >> 3, p = n & 7;
      int col = (p ^ (r & 7)) << 3;
      gload16(sa + (size_t)(i0 + r) * DD + kk0 + col, &lds[b][n << 3]);
      gload16(sb + (size_t)(j0 + r) * DD + kk0 + col, &lds[b][8192 + (n << 3)]);
    }
  };

  stage(0, 0);
  int cur = 0;
  for (int s = 0; s < 48; ++s) {
    if (s < 47) {
      stage(cur ^ 1, s + 1);
      asm volatile("s_waitcnt vmcnt(8)" ::: "memory");
    } else {
      asm volatile("s_waitcnt vmcnt(0)" ::: "memory");
    }
    __builtin_amdgcn_s_barrier();
#pragma unroll
    for (int kk = 0; kk < 2; ++kk) {
      int g = (kk << 2) + kslot;
      short8 av[4], bv[4];
#pragma unroll
      for (int m = 0; m < 4; ++m) {
        int r = (wr << 6) + (m << 4) + arow_l;
        av[m] = *(const short8*)&lds[cur][(r << 6) + ((g ^ (r & 7)) << 3)];
      }
#pragma unroll
      for (int n = 0; n < 4; ++n) {
        int r = (wc << 6) + (n << 4) + arow_l;
        bv[n] = *(const short8*)&lds[cur][8192 + (r << 6) + ((g ^ (r & 7)) << 3)];
      }
#pragma unroll
      for (int m = 0; m < 4; ++m)
#pragma unroll
        for (int n = 0; n < 4; ++n)
          acc[m][n] = __builtin_amdgcn_mfma_f32_16x16x32_bf16(av[m], bv[n], acc[m][n], 0, 0, 0);
    }
    asm volatile("s_waitcnt lgkmcnt(0)" ::: "memory");
    __builtin_amdgcn_s_barrier();
    cur ^= 1;
  }
  int rbase = (l >> 4) << 2;
#pragma unroll
  for (int m = 0; m < 4; ++m) {
#pragma unroll
    for (int n = 0; n < 4; ++n) {
#pragma unroll
      for (int r = 0; r < 4; ++r) {
        int gi = i0 + (wr << 6) + (m << 4) + rbase + r;
        int gj = j0 + (wc << 6) + (n << 4) + (l & 15);
        float v = fmaxf(acc[m][n][r], 0.0f);
        if (gi == gj) v = 1.0f;
        A[(size_t)gi * NN + gj] = v;
      }
    }
  }
  // mirror via LDS transpose: two chunks of T[128 local_j][68 pad]
  if (bi != bj) {
    float* T = (float*)&lds[0][0];  // 34816 B
#pragma unroll
    for (int c2 = 0; c2 < 2; ++c2) {
      __syncthreads();
      if (wr == c2) {
#pragma unroll
        for (int m = 0; m < 4; ++m)
#pragma unroll
          for (int n = 0; n < 4; ++n)
#pragma unroll
            for (int r = 0; r < 4; ++r)
              T[(((wc << 6) + (n << 4) + (l & 15)) * 68) + (m << 4) + rbase + r] =
                  fmaxf(acc[m][n][r], 0.0f);
      }
      __syncthreads();
      int lj = t >> 1, cg = (t & 1) << 5;
#pragma unroll
      for (int q = 0; q < 8; ++q) {
        float4 vq = *(const float4*)&T[lj * 68 + cg + (q << 2)];
        *(float4*)&A[(size_t)(j0 + lj) * NN + i0 + (c2 << 6) + cg + (q << 2)] = vq;
      }
    }
  }
}

// ---------------- sigma[i] = 7th largest of row i (float4 loads) ----------------
__device__ __forceinline__ void ins7(float (&tv)[7], float v) {
  if (v > tv[6]) {
#pragma unroll
    for (int s = 0; s < 7; s++) {
      if (v > tv[s]) { float tmp = tv[s]; tv[s] = v; v = tmp; }
    }
  }
}
__global__ __launch_bounds__(256) void k_top7(const float* __restrict__ A,
                                              float* __restrict__ sig) {
  int w = threadIdx.x >> 6, lane = threadIdx.x & 63;
  int row = (blockIdx.x << 2) + w;
  const float4* a4 = (const float4*)(A + (size_t)row * NN);
  float tv[7];
#pragma unroll
  for (int i = 0; i < 7; i++) tv[i] = -1.0f;
  for (int k = 0; k < 16; k++) {
    float4 v = a4[(k << 6) + lane];
    ins7(tv, v.x); ins7(tv, v.y); ins7(tv, v.z); ins7(tv, v.w);
  }
  int head = 0;
  float seventh = 0.0f;
  for (int r = 0; r < 7; r++) {
    float h = (head < 7) ? tv[head] : -1.0f;
    float m = h;
#pragma unroll
    for (int off = 32; off; off >>= 1) m = fmaxf(m, __shfl_xor(m, off));
    unsigned long long ball = __ballot(h == m);
    if (lane == (__ffsll(ball) - 1)) head++;
    seventh = m;
  }
  if (lane == 0) sig[row] = seventh;
}

// ---------------- transform all rows for mean; store only bottom half ----------------
__global__ __launch_bounds__(256) void k_transform(float* __restrict__ A,
                                                   const float* __restrict__ sig,
                                                   double* __restrict__ parts) {
  int row = blockIdx.x;
  float si = sig[row];
  float4* a4 = (float4*)(A + (size_t)row * NN);
  const float4* s4 = (const float4*)sig;
  int t = threadIdx.x;
  bool store = (row >= NLAB);
  double local = 0.0;
#pragma unroll
  for (int k = 0; k < 4; k++) {
    int j = (k << 8) + t;
    float4 v = a4[j];
    float4 sg = s4[j];
    float4 ww;
    ww.x = expf(-(v.x * v.x) / (si * sg.x));
    ww.y = expf(-(v.y * v.y) / (si * sg.y));
    ww.z = expf(-(v.z * v.z) / (si * sg.z));
    ww.w = expf(-(v.w * v.w) / (si * sg.w));
    if (store) a4[j] = ww;
    local += (double)ww.x + (double)ww.y + (double)ww.z + (double)ww.w;
  }
  __shared__ double dred[4];
  int lane = t & 63, wv = t >> 6;
#pragma unroll
  for (int off = 32; off; off >>= 1) local += __shfl_xor(local, off);
  if (lane == 0) dred[wv] = local;
  __syncthreads();
  if (t == 0) parts[row] = dred[0] + dred[1] + dred[2] + dred[3];
}

__global__ __launch_bounds__(256) void k_mean(const double* __restrict__ parts,
                                              float* __restrict__ meanb) {
  int t = threadIdx.x;
  double local = 0.0;
#pragma unroll
  for (int k = 0; k < NN / 256; k++) local += parts[(k << 8) + t];
  __shared__ double dred[4];
  int lane = t & 63, wv = t >> 6;
#pragma unroll
  for (int off = 32; off; off >>= 1) local += __shfl_xor(local, off);
  if (lane == 0) dred[wv] = local;
  __syncthreads();
  if (t == 0) meanb[0] = (float)((dred[0] + dred[1] + dred[2] + dred[3]) / ((double)NN * (double)NN));
}

// ---------------- threshold bottom half -> bf16 (hi only) ----------------
__global__ __launch_bounds__(256) void k_thresh_bf(const float* __restrict__ A,
                                                   const float* __restrict__ meanb,
                                                   ushortT* __restrict__ Abh) {
  float m = meanb[0];
  size_t i4 = ((size_t)blockIdx.x << 8) + threadIdx.x;  // over 2048*4096/4
  float4 v = ((const float4*)(A + (size_t)NLAB * NN))[i4];
  float c0 = (v.x < m) ? 0.0f : v.x;
  float c1 = (v.y < m) ? 0.0f : v.y;
  float c2 = (v.z < m) ? 0.0f : v.z;
  float c3 = (v.w < m) ? 0.0f : v.w;
  ushort4 hv;
  hv.x = bf16rn(c0); hv.y = bf16rn(c1); hv.z = bf16rn(c2); hv.w = bf16rn(c3);
  ((ushort4*)Abh)[i4] = hv;
}

// ---------------- one-hot labels, transposed bf16 [128][2048] ----------------
__global__ __launch_bounds__(256) void k_xlabt(const int* __restrict__ labels,
                                               ushortT* __restrict__ Xlabt) {
  int idx = (blockIdx.x << 8) + threadIdx.x;  // 262144
  int c = idx >> 11, j = idx & 2047;
  Xlabt[idx] = (labels[j] == c) ? (ushortT)0x3F80 : (ushortT)0;
}

// ---------------- X init: fp32 [2048][128] + transposed bf16 ----------------
__global__ __launch_bounds__(256) void k_xinit(float* __restrict__ Xf,
                                               ushortT* __restrict__ Xth) {
  int idx = (blockIdx.x << 8) + threadIdx.x;  // 262144 over [2048][128]
  int i = idx >> 7, c = idx & 127;
  float v = (c < NC) ? 0.01f : 0.0f;
  Xf[idx] = v;
  Xth[(size_t)c * NLAB + i] = bf16rn(v);
}

// ---------------- fused per-iteration kernel: mm = Ah@X^T; rowsum; update ----------
// 128 blocks x 512 thr; 16 rows/block; wave K-split 256; XCD-pinned row slabs.
template <bool UPDATE>
__global__ __launch_bounds__(512) void k_it(
    const ushortT* __restrict__ Ah, int acol0,
    const ushortT* __restrict__ Xt,  // [128][2048] bf16 transposed
    const float* __restrict__ YlabF, const float* __restrict__ Xprev,
    float* __restrict__ outF, ushortT* __restrict__ outT) {
  __shared__ float red[8 * 16 * 132];  // [wave][row16][col pad132] = 67.6 KB
  int t = threadIdx.x, l = t & 63, w = t >> 6;
  int bid = (int)blockIdx.x;
  int rg = ((bid & 7) << 4) + (bid >> 3);  // XCD x owns rows x*256..x*256+255
  int brow0 = rg << 4;
  int arow = l & 15, khi = l >> 4;
  int rb = khi << 2;

  f32x4 acc[8];
#pragma unroll
  for (int n = 0; n < 8; ++n) acc[n] = (f32x4){0.f, 0.f, 0.f, 0.f};
  const ushortT* ap = Ah + (size_t)(brow0 + arow) * NN + acol0 + (w << 8) + (khi << 3);
  const ushortT* xp = Xt + (size_t)arow * NLAB + (w << 8) + (khi << 3);
#pragma unroll
  for (int g = 0; g < 8; ++g) {
    short8 av = *(const short8*)(ap + (g << 5));
#pragma unroll
    for (int n = 0; n < 8; ++n) {
      short8 bv = *(const short8*)(xp + ((size_t)(n << 4)) * NLAB + (g << 5));
      acc[n] = __builtin_amdgcn_mfma_f32_16x16x32_bf16(av, bv, acc[n], 0, 0, 0);
    }
  }
#pragma unroll
  for (int n = 0; n < 8; ++n)
#pragma unroll
    for (int rr = 0; rr < 4; ++rr)
      red[((w << 4) + rb + rr) * 132 + (n << 4) + arow] = acc[n][rr];
  __syncthreads();

  int row = t >> 5, c4 = (t & 31) << 2;
  int gi = brow0 + row;
  float4 s4 = {0.f, 0.f, 0.f, 0.f};
#pragma unroll
  for (int w2 = 0; w2 < 8; ++w2) {
    float4 p = *(const float4*)&red[((w2 << 4) + row) * 132 + c4];
    s4.x += p.x; s4.y += p.y; s4.z += p.z; s4.w += p.w;
  }
  size_t o = (size_t)gi * CP + c4;
  if constexpr (!UPDATE) {
    *(float4*)&outF[o] = s4;
  } else {
    float4 yl = *(const float4*)&YlabF[o];
    float4 xv = *(const float4*)&Xprev[o];
    float mult[4];
    mult[0] = fmaf(xv.x, s4.x + yl.x, xv.x);
    mult[1] = fmaf(xv.y, s4.y + yl.y, xv.y);
    mult[2] = fmaf(xv.z, s4.z + yl.z, xv.z);
    mult[3] = fmaf(xv.w, s4.w + yl.w, xv.w);
    float s = mult[0] + mult[1] + mult[2] + mult[3];
#pragma unroll
    for (int off = 16; off; off >>= 1) s += __shfl_xor(s, off);
    float denom = s + 1e-8f;
    float4 ov;
    ov.x = mult[0] / denom; ov.y = mult[1] / denom;
    ov.z = mult[2] / denom; ov.w = mult[3] / denom;
    *(float4*)&outF[o] = ov;
    outT[(size_t)(c4 + 0) * NLAB + gi] = bf16rn(ov.x);
    outT[(size_t)(c4 + 1) * NLAB + gi] = bf16rn(ov.y);
    outT[(size_t)(c4 + 2) * NLAB + gi] = bf16rn(ov.z);
    outT[(size_t)(c4 + 3) * NLAB + gi] = bf16rn(ov.w);
  }
}

// ---------------- output assembly ----------------
__global__ __launch_bounds__(256) void k_output(const float* __restrict__ Xf,
                                                const int* __restrict__ labels,
                                                float* __restrict__ out) {
  int idx = (blockIdx.x << 8) + threadIdx.x;  // 409600
  int i = idx / NC, c = idx - i * NC;
  float v;
  if (i < NLAB) v = (labels[i] == c) ? 1.0f : 0.0f;
  else v = Xf[((size_t)(i - NLAB) << 7) + c];
  out[idx] = v;
}

extern "C" void kernel_launch(void* const* d_in, const int* in_sizes, int n_in,
                              void* d_out, int out_size, void* d_ws, size_t ws_size,
                              hipStream_t stream) {
  const float* E = (const float*)d_in[0];
  const int* labels = (const int*)d_in[1];
  float* out = (float*)d_out;
  char* ws = (char*)d_ws;
  const size_t MB = 1024 * 1024;

  float* A = (float*)ws;                          // 64 MB (dead after thresh_bf)
  ushortT* Enh = (ushortT*)(ws + 64 * MB);        // 8 MB
  ushortT* Enl = (ushortT*)(ws + 72 * MB);        // 8 MB
  ushortT* Abh = (ushortT*)(ws + 80 * MB);        // 16 MB [2048][4096] bf16
  float* sig = (float*)(ws + 96 * MB);
  double* parts = (double*)(ws + 96 * MB + 65536);
  float* meanb = (float*)(ws + 96 * MB + 131072);
  ushortT* Xlabt = (ushortT*)(ws + 97 * MB);      // 0.5 MB [128][2048]
  float* YlabF = (float*)(ws + 98 * MB);          // 1 MB
  float* Xf0 = (float*)(ws + 99 * MB);            // 1 MB
  float* Xf1 = (float*)(ws + 100 * MB);           // 1 MB
  ushortT* Xt0 = (ushortT*)(ws + 101 * MB);       // 0.5 MB
  ushortT* Xt1 = (ushortT*)(ws + 102 * MB);       // 0.5 MB

  k_normalize<<<NN, 256, 0, stream>>>(E, Enh, Enl);
  k_syrk_mfma<<<528, 256, 0, stream>>>(Enh, Enl, A);
  k_top7<<<NN / 4, 256, 0, stream>>>(A, sig);
  k_transform<<<NN, 256, 0, stream>>>(A, sig, parts);
  k_mean<<<1, 256, 0, stream>>>(parts, meanb);
  k_thresh_bf<<<8192, 256, 0, stream>>>(A, meanb, Abh);
  k_xlabt<<<1024, 256, 0, stream>>>(labels, Xlabt);
  k_xinit<<<1024, 256, 0, stream>>>(Xf0, Xt0);
  // Ylab = Ah[unlab, :2048] @ onehot
  k_it<false><<<128, 512, 0, stream>>>(Abh, 0, Xlabt, nullptr, nullptr, YlabF, nullptr);
  float* xf[2] = {Xf0, Xf1};
  ushortT* xt[2] = {Xt0, Xt1};
  int cur = 0;
  for (int it = 0; it < NITER; ++it) {
    int nxt = cur ^ 1;
    k_it<true><<<128, 512, 0, stream>>>(Abh, NLAB, xt[cur], YlabF, xf[cur],
                                        xf[nxt], xt[nxt]);
    cur = nxt;
  }
  k_output<<<1600, 256, 0, stream>>>(xf[cur], labels, out);
}

// Round 7
// 720.484 us; speedup vs baseline: 3.0255x; 1.0545x over previous
//
#include <hip/hip_runtime.h>
#include <math.h>

typedef unsigned short ushortT;
typedef __attribute__((ext_vector_type(8))) short short8;
typedef __attribute__((ext_vector_type(4))) float f32x4;

#define NN 4096
#define DD 1024
#define NC 100
#define CP 128
#define NLAB 2048
#define NITER 30

__device__ __forceinline__ ushortT bf16rn(float x) {
  unsigned u = __float_as_uint(x);
  unsigned r = (u + 0x7fffu + ((u >> 16) & 1u)) >> 16;
  return (ushortT)r;
}
__device__ __forceinline__ float bf2f(ushortT h) {
  return __uint_as_float(((unsigned)h) << 16);
}
__device__ __forceinline__ void gload16(const void* g, void* l) {
  __builtin_amdgcn_global_load_lds((const __attribute__((address_space(1))) char*)g,
                                   (__attribute__((address_space(3))) char*)l, 16, 0, 0);
}

// ---------------- normalize rows -> bf16 hi/lo splits ----------------
__global__ __launch_bounds__(256) void k_normalize(const float* __restrict__ E,
                                                   ushortT* __restrict__ Enh,
                                                   ushortT* __restrict__ Enl) {
  int row = blockIdx.x, t = threadIdx.x;
  const float4* e4 = (const float4*)(E + (size_t)row * DD);
  float4 v = e4[t];
  float ss = v.x * v.x + v.y * v.y + v.z * v.z + v.w * v.w;
  __shared__ float red[4];
  int lane = t & 63, w = t >> 6;
#pragma unroll
  for (int off = 32; off; off >>= 1) ss += __shfl_xor(ss, off);
  if (lane == 0) red[w] = ss;
  __syncthreads();
  float tot = red[0] + red[1] + red[2] + red[3];
  float d = fmaxf(sqrtf(tot), 1e-12f);
  float xs[4] = {v.x / d, v.y / d, v.z / d, v.w / d};
  ushort4 hv, lv;
  ushortT h;
  h = bf16rn(xs[0]); hv.x = h; lv.x = bf16rn(xs[0] - bf2f(h));
  h = bf16rn(xs[1]); hv.y = h; lv.y = bf16rn(xs[1] - bf2f(h));
  h = bf16rn(xs[2]); hv.z = h; lv.z = bf16rn(xs[2] - bf2f(h));
  h = bf16rn(xs[3]); hv.w = h; lv.w = bf16rn(xs[3] - bf2f(h));
  ((ushort4*)Enh)[(size_t)row * 256 + t] = hv;
  ((ushort4*)Enl)[(size_t)row * 256 + t] = lv;
}

// ---------------- A0 = relu(En@En^T) via MFMA, 3-term bf16 split; diag=1 ----------------
// Upper-tri block grid (528); mirror via LDS transpose; 2 blocks/CU.
__global__ __launch_bounds__(256, 2) void k_syrk_mfma(const ushortT* __restrict__ Enh,
                                                      const ushortT* __restrict__ Enl,
                                                      float* __restrict__ A) {
  __shared__ ushortT lds[2][16384];  // per buf: A-tile [128][64] @0, B-tile @8192
  int t = threadIdx.x;
  int l = t & 63, w = t >> 6;
  int rem = blockIdx.x, bi = 0;
  while (rem >= (32 - bi)) { rem -= (32 - bi); ++bi; }
  int bj = bi + rem;
  int i0 = bi << 7, j0 = bj << 7;
  int wr = w >> 1, wc = w & 1;
  f32x4 zz = {0.f, 0.f, 0.f, 0.f};
  f32x4 acc[4][4];
#pragma unroll
  for (int m = 0; m < 4; ++m)
#pragma unroll
    for (int n = 0; n < 4; ++n) acc[m][n] = zz;
  int arow_l = l & 15, kslot = l >> 4;

  auto stage = [&](int b, int s) {
    int term = s >> 4;
    int kk0 = (s & 15) << 6;
    const ushortT* sa = (term == 2) ? Enl : Enh;
    const ushortT* sb = (term == 1) ? Enl : Enh;
#pragma unroll
    for (int q = 0; q < 4; ++q) {
      int n = (q << 8) + t;
      int r = n >> 3, p = n & 7;
      int col = (p ^ (r & 7)) << 3;
      gload16(sa + (size_t)(i0 + r) * DD + kk0 + col, &lds[b][n << 3]);
      gload16(sb + (size_t)(j0 + r) * DD + kk0 + col, &lds[b][8192 + (n << 3)]);
    }
  };

  stage(0, 0);
  int cur = 0;
  for (int s = 0; s < 48; ++s) {
    if (s < 47) {
      stage(cur ^ 1, s + 1);
      asm volatile("s_waitcnt vmcnt(8)" ::: "memory");
    } else {
      asm volatile("s_waitcnt vmcnt(0)" ::: "memory");
    }
    __builtin_amdgcn_s_barrier();
#pragma unroll
    for (int kk = 0; kk < 2; ++kk) {
      int g = (kk << 2) + kslot;
      short8 av[4], bv[4];
#pragma unroll
      for (int m = 0; m < 4; ++m) {
        int r = (wr << 6) + (m << 4) + arow_l;
        av[m] = *(const short8*)&lds[cur][(r << 6) + ((g ^ (r & 7)) << 3)];
      }
#pragma unroll
      for (int n = 0; n < 4; ++n) {
        int r = (wc << 6) + (n << 4) + arow_l;
        bv[n] = *(const short8*)&lds[cur][8192 + (r << 6) + ((g ^ (r & 7)) << 3)];
      }
#pragma unroll
      for (int m = 0; m < 4; ++m)
#pragma unroll
        for (int n = 0; n < 4; ++n)
          acc[m][n] = __builtin_amdgcn_mfma_f32_16x16x32_bf16(av[m], bv[n], acc[m][n], 0, 0, 0);
    }
    asm volatile("s_waitcnt lgkmcnt(0)" ::: "memory");
    __builtin_amdgcn_s_barrier();
    cur ^= 1;
  }
  int rbase = (l >> 4) << 2;
#pragma unroll
  for (int m = 0; m < 4; ++m) {
#pragma unroll
    for (int n = 0; n < 4; ++n) {
#pragma unroll
      for (int r = 0; r < 4; ++r) {
        int gi = i0 + (wr << 6) + (m << 4) + rbase + r;
        int gj = j0 + (wc << 6) + (n << 4) + (l & 15);
        float v = fmaxf(acc[m][n][r], 0.0f);
        if (gi == gj) v = 1.0f;
        A[(size_t)gi * NN + gj] = v;
      }
    }
  }
  // mirror via LDS transpose: two chunks of T[128 local_j][68 pad]
  if (bi != bj) {
    float* T = (float*)&lds[0][0];  // 34816 B
#pragma unroll
    for (int c2 = 0; c2 < 2; ++c2) {
      __syncthreads();
      if (wr == c2) {
#pragma unroll
        for (int m = 0; m < 4; ++m)
#pragma unroll
          for (int n = 0; n < 4; ++n)
#pragma unroll
            for (int r = 0; r < 4; ++r)
              T[(((wc << 6) + (n << 4) + (l & 15)) * 68) + (m << 4) + rbase + r] =
                  fmaxf(acc[m][n][r], 0.0f);
      }
      __syncthreads();
      int lj = t >> 1, cg = (t & 1) << 5;
#pragma unroll
      for (int q = 0; q < 8; ++q) {
        float4 vq = *(const float4*)&T[lj * 68 + cg + (q << 2)];
        *(float4*)&A[(size_t)(j0 + lj) * NN + i0 + (c2 << 6) + cg + (q << 2)] = vq;
      }
    }
  }
}

// ---------------- sigma[i] = 7th largest of row i (float4 loads) ----------------
__device__ __forceinline__ void ins7(float (&tv)[7], float v) {
  if (v > tv[6]) {
#pragma unroll
    for (int s = 0; s < 7; s++) {
      if (v > tv[s]) { float tmp = tv[s]; tv[s] = v; v = tmp; }
    }
  }
}
__global__ __launch_bounds__(256) void k_top7(const float* __restrict__ A,
                                              float* __restrict__ sig) {
  int w = threadIdx.x >> 6, lane = threadIdx.x & 63;
  int row = (blockIdx.x << 2) + w;
  const float4* a4 = (const float4*)(A + (size_t)row * NN);
  float tv[7];
#pragma unroll
  for (int i = 0; i < 7; i++) tv[i] = -1.0f;
  for (int k = 0; k < 16; k++) {
    float4 v = a4[(k << 6) + lane];
    ins7(tv, v.x); ins7(tv, v.y); ins7(tv, v.z); ins7(tv, v.w);
  }
  int head = 0;
  float seventh = 0.0f;
  for (int r = 0; r < 7; r++) {
    float h = (head < 7) ? tv[head] : -1.0f;
    float m = h;
#pragma unroll
    for (int off = 32; off; off >>= 1) m = fmaxf(m, __shfl_xor(m, off));
    unsigned long long ball = __ballot(h == m);
    if (lane == (__ffsll(ball) - 1)) head++;
    seventh = m;
  }
  if (lane == 0) sig[row] = seventh;
}

// ---------------- transform all rows for mean; store only bottom half ----------------
__global__ __launch_bounds__(256) void k_transform(float* __restrict__ A,
                                                   const float* __restrict__ sig,
                                                   double* __restrict__ parts) {
  int row = blockIdx.x;
  float si = sig[row];
  float4* a4 = (float4*)(A + (size_t)row * NN);
  const float4* s4 = (const float4*)sig;
  int t = threadIdx.x;
  bool store = (row >= NLAB);
  double local = 0.0;
#pragma unroll
  for (int k = 0; k < 4; k++) {
    int j = (k << 8) + t;
    float4 v = a4[j];
    float4 sg = s4[j];
    float4 ww;
    ww.x = expf(-(v.x * v.x) / (si * sg.x));
    ww.y = expf(-(v.y * v.y) / (si * sg.y));
    ww.z = expf(-(v.z * v.z) / (si * sg.z));
    ww.w = expf(-(v.w * v.w) / (si * sg.w));
    if (store) a4[j] = ww;
    local += (double)ww.x + (double)ww.y + (double)ww.z + (double)ww.w;
  }
  __shared__ double dred[4];
  int lane = t & 63, wv = t >> 6;
#pragma unroll
  for (int off = 32; off; off >>= 1) local += __shfl_xor(local, off);
  if (lane == 0) dred[wv] = local;
  __syncthreads();
  if (t == 0) parts[row] = dred[0] + dred[1] + dred[2] + dred[3];
}

__global__ __launch_bounds__(256) void k_mean(const double* __restrict__ parts,
                                              float* __restrict__ meanb) {
  int t = threadIdx.x;
  double local = 0.0;
#pragma unroll
  for (int k = 0; k < NN / 256; k++) local += parts[(k << 8) + t];
  __shared__ double dred[4];
  int lane = t & 63, wv = t >> 6;
#pragma unroll
  for (int off = 32; off; off >>= 1) local += __shfl_xor(local, off);
  if (lane == 0) dred[wv] = local;
  __syncthreads();
  if (t == 0) meanb[0] = (float)((dred[0] + dred[1] + dred[2] + dred[3]) / ((double)NN * (double)NN));
}

// ---------------- threshold bottom half -> bf16 (hi only) ----------------
__global__ __launch_bounds__(256) void k_thresh_bf(const float* __restrict__ A,
                                                   const float* __restrict__ meanb,
                                                   ushortT* __restrict__ Abh) {
  float m = meanb[0];
  size_t i4 = ((size_t)blockIdx.x << 8) + threadIdx.x;  // over 2048*4096/4
  float4 v = ((const float4*)(A + (size_t)NLAB * NN))[i4];
  float c0 = (v.x < m) ? 0.0f : v.x;
  float c1 = (v.y < m) ? 0.0f : v.y;
  float c2 = (v.z < m) ? 0.0f : v.z;
  float c3 = (v.w < m) ? 0.0f : v.w;
  ushort4 hv;
  hv.x = bf16rn(c0); hv.y = bf16rn(c1); hv.z = bf16rn(c2); hv.w = bf16rn(c3);
  ((ushort4*)Abh)[i4] = hv;
}

// ---------------- one-hot labels, transposed bf16 [128][2048] ----------------
__global__ __launch_bounds__(256) void k_xlabt(const int* __restrict__ labels,
                                               ushortT* __restrict__ Xlabt) {
  int idx = (blockIdx.x << 8) + threadIdx.x;  // 262144
  int c = idx >> 11, j = idx & 2047;
  Xlabt[idx] = (labels[j] == c) ? (ushortT)0x3F80 : (ushortT)0;
}

// ---------------- X init: fp32 [2048][128] + transposed bf16 ----------------
__global__ __launch_bounds__(256) void k_xinit(float* __restrict__ Xf,
                                               ushortT* __restrict__ Xth) {
  int idx = (blockIdx.x << 8) + threadIdx.x;  // 262144 over [2048][128]
  int i = idx >> 7, c = idx & 127;
  float v = (c < NC) ? 0.01f : 0.0f;
  Xf[idx] = v;
  Xth[(size_t)c * NLAB + i] = bf16rn(v);
}

// ---------------- P: partial GEMM. 512 blocks = 32 rg x 16 s; 256 thr (4 waves).
// Block (rg,s): rows rg*64..+64, K-slice s*128..+128. Wave owns 16 complete rows
// (no reduce, no LDS). XCD-pinned by s (bid&7). Writes bf16 partial slice.
__global__ __launch_bounds__(256) void k_gP(const ushortT* __restrict__ Ah, int acol0,
                                            const ushortT* __restrict__ Xt,
                                            ushortT* __restrict__ Pp) {
  int t = threadIdx.x, l = t & 63, w = t >> 6;
  int bid = (int)blockIdx.x;
  int x = bid & 7, rest = bid >> 3;
  int s = x + ((rest & 1) << 3);   // 0..15
  int rg = rest >> 1;              // 0..31
  int arow = l & 15, khi = l >> 4;
  int grow = (rg << 6) + (w << 4) + arow;
  const ushortT* ap = Ah + (size_t)grow * NN + acol0 + (s << 7) + (khi << 3);
  const ushortT* xp = Xt + (size_t)arow * NLAB + (s << 7) + (khi << 3);

  short8 av[4];
#pragma unroll
  for (int ks = 0; ks < 4; ++ks) av[ks] = *(const short8*)(ap + (ks << 5));
  f32x4 acc[8];
#pragma unroll
  for (int cf = 0; cf < 8; ++cf) {
    acc[cf] = (f32x4){0.f, 0.f, 0.f, 0.f};
    const ushortT* xc = xp + ((size_t)(cf << 4)) * NLAB;
#pragma unroll
    for (int ks = 0; ks < 4; ++ks) {
      short8 bv = *(const short8*)(xc + (ks << 5));
      acc[cf] = __builtin_amdgcn_mfma_f32_16x16x32_bf16(av[ks], bv, acc[cf], 0, 0, 0);
    }
  }
  // write partial: row = rg*64 + w*16 + khi*4 + r, col = cf*16 + arow
  int orow = (rg << 6) + (w << 4) + (khi << 2);
  ushortT* pb = Pp + ((size_t)s << 18) + ((size_t)orow << 7) + arow;
#pragma unroll
  for (int cf = 0; cf < 8; ++cf) {
#pragma unroll
    for (int r = 0; r < 4; ++r)
      pb[(size_t)(r << 7) + (cf << 4)] = bf16rn(acc[cf][r]);
  }
}

// ---------------- U: reduce 16 partial slices + fused update ----------------
template <bool UPDATE>
__global__ __launch_bounds__(256) void k_updU(
    const ushortT* __restrict__ Pp,
    const float* __restrict__ YlabF, const float* __restrict__ Xprev,
    float* __restrict__ outF, ushortT* __restrict__ outT) {
  int t = threadIdx.x;
  int row = ((int)blockIdx.x << 3) + (t >> 5);
  int c4 = (t & 31) << 2;
  size_t o = ((size_t)row << 7) + c4;
  float4 s4 = {0.f, 0.f, 0.f, 0.f};
#pragma unroll
  for (int s = 0; s < 16; ++s) {
    ushort4 pv = *(const ushort4*)&Pp[((size_t)s << 18) + o];
    s4.x += bf2f(pv.x); s4.y += bf2f(pv.y); s4.z += bf2f(pv.z); s4.w += bf2f(pv.w);
  }
  if constexpr (!UPDATE) {
    *(float4*)&outF[o] = s4;
  } else {
    float4 yl = *(const float4*)&YlabF[o];
    float4 xv = *(const float4*)&Xprev[o];
    float mult[4];
    mult[0] = fmaf(xv.x, s4.x + yl.x, xv.x);
    mult[1] = fmaf(xv.y, s4.y + yl.y, xv.y);
    mult[2] = fmaf(xv.z, s4.z + yl.z, xv.z);
    mult[3] = fmaf(xv.w, s4.w + yl.w, xv.w);
    float s = mult[0] + mult[1] + mult[2] + mult[3];
#pragma unroll
    for (int off = 16; off; off >>= 1) s += __shfl_xor(s, off);
    float denom = s + 1e-8f;
    float4 ov;
    ov.x = mult[0] / denom; ov.y = mult[1] / denom;
    ov.z = mult[2] / denom; ov.w = mult[3] / denom;
    *(float4*)&outF[o] = ov;
    outT[(size_t)(c4 + 0) * NLAB + row] = bf16rn(ov.x);
    outT[(size_t)(c4 + 1) * NLAB + row] = bf16rn(ov.y);
    outT[(size_t)(c4 + 2) * NLAB + row] = bf16rn(ov.z);
    outT[(size_t)(c4 + 3) * NLAB + row] = bf16rn(ov.w);
  }
}

// ---------------- output assembly ----------------
__global__ __launch_bounds__(256) void k_output(const float* __restrict__ Xf,
                                                const int* __restrict__ labels,
                                                float* __restrict__ out) {
  int idx = (blockIdx.x << 8) + threadIdx.x;  // 409600
  int i = idx / NC, c = idx - i * NC;
  float v;
  if (i < NLAB) v = (labels[i] == c) ? 1.0f : 0.0f;
  else v = Xf[((size_t)(i - NLAB) << 7) + c];
  out[idx] = v;
}

extern "C" void kernel_launch(void* const* d_in, const int* in_sizes, int n_in,
                              void* d_out, int out_size, void* d_ws, size_t ws_size,
                              hipStream_t stream) {
  const float* E = (const float*)d_in[0];
  const int* labels = (const int*)d_in[1];
  float* out = (float*)d_out;
  char* ws = (char*)d_ws;
  const size_t MB = 1024 * 1024;

  float* A = (float*)ws;                          // 64 MB (dead after thresh_bf)
  ushortT* Enh = (ushortT*)(ws + 64 * MB);        // 8 MB
  ushortT* Enl = (ushortT*)(ws + 72 * MB);        // 8 MB
  ushortT* Abh = (ushortT*)(ws + 80 * MB);        // 16 MB [2048][4096] bf16
  float* sig = (float*)(ws + 96 * MB);
  double* parts = (double*)(ws + 96 * MB + 65536);
  float* meanb = (float*)(ws + 96 * MB + 131072);
  ushortT* Xlabt = (ushortT*)(ws + 97 * MB);      // 0.5 MB [128][2048]
  float* YlabF = (float*)(ws + 98 * MB);          // 1 MB
  float* Xf0 = (float*)(ws + 99 * MB);            // 1 MB
  float* Xf1 = (float*)(ws + 100 * MB);           // 1 MB
  ushortT* Xt0 = (ushortT*)(ws + 101 * MB);       // 0.5 MB
  ushortT* Xt1 = (ushortT*)(ws + 102 * MB);       // 0.5 MB
  ushortT* Pp = (ushortT*)(ws + 104 * MB);        // 8 MB [16][2048][128] bf16

  k_normalize<<<NN, 256, 0, stream>>>(E, Enh, Enl);
  k_syrk_mfma<<<528, 256, 0, stream>>>(Enh, Enl, A);
  k_top7<<<NN / 4, 256, 0, stream>>>(A, sig);
  k_transform<<<NN, 256, 0, stream>>>(A, sig, parts);
  k_mean<<<1, 256, 0, stream>>>(parts, meanb);
  k_thresh_bf<<<8192, 256, 0, stream>>>(A, meanb, Abh);
  k_xlabt<<<1024, 256, 0, stream>>>(labels, Xlabt);
  k_xinit<<<1024, 256, 0, stream>>>(Xf0, Xt0);
  // Ylab = Ah[unlab, :2048] @ onehot, via P + U<false>
  k_gP<<<512, 256, 0, stream>>>(Abh, 0, Xlabt, Pp);
  k_updU<false><<<256, 256, 0, stream>>>(Pp, nullptr, nullptr, YlabF, nullptr);
  float* xf[2] = {Xf0, Xf1};
  ushortT* xt[2] = {Xt0, Xt1};
  int cur = 0;
  for (int it = 0; it < NITER; ++it) {
    int nxt = cur ^ 1;
    k_gP<<<512, 256, 0, stream>>>(Abh, NLAB, xt[cur], Pp);
    k_updU<true><<<256, 256, 0, stream>>>(Pp, YlabF, xf[cur], xf[nxt], xt[nxt]);
    cur = nxt;
  }
  k_output<<<1600, 256, 0, stream>>>(xf[cur], labels, out);
}

// Round 8
// 593.639 us; speedup vs baseline: 3.6720x; 1.2137x over previous
//
#include <hip/hip_runtime.h>
#include <math.h>

typedef unsigned short ushortT;
typedef __attribute__((ext_vector_type(8))) short short8;
typedef __attribute__((ext_vector_type(4))) float f32x4;

#define NN 4096
#define DD 1024
#define NC 100
#define CP 128
#define NLAB 2048
#define NITER 30

__device__ __forceinline__ ushortT bf16rn(float x) {
  unsigned u = __float_as_uint(x);
  unsigned r = (u + 0x7fffu + ((u >> 16) & 1u)) >> 16;
  return (ushortT)r;
}
__device__ __forceinline__ float bf2f(ushortT h) {
  return __uint_as_float(((unsigned)h) << 16);
}
__device__ __forceinline__ void gload16(const void* g, void* l) {
  __builtin_amdgcn_global_load_lds((const __attribute__((address_space(1))) char*)g,
                                   (__attribute__((address_space(3))) char*)l, 16, 0, 0);
}

// ---------------- normalize rows -> bf16 hi/lo splits ----------------
__global__ __launch_bounds__(256) void k_normalize(const float* __restrict__ E,
                                                   ushortT* __restrict__ Enh,
                                                   ushortT* __restrict__ Enl) {
  int row = blockIdx.x, t = threadIdx.x;
  const float4* e4 = (const float4*)(E + (size_t)row * DD);
  float4 v = e4[t];
  float ss = v.x * v.x + v.y * v.y + v.z * v.z + v.w * v.w;
  __shared__ float red[4];
  int lane = t & 63, w = t >> 6;
#pragma unroll
  for (int off = 32; off; off >>= 1) ss += __shfl_xor(ss, off);
  if (lane == 0) red[w] = ss;
  __syncthreads();
  float tot = red[0] + red[1] + red[2] + red[3];
  float d = fmaxf(sqrtf(tot), 1e-12f);
  float xs[4] = {v.x / d, v.y / d, v.z / d, v.w / d};
  ushort4 hv, lv;
  ushortT h;
  h = bf16rn(xs[0]); hv.x = h; lv.x = bf16rn(xs[0] - bf2f(h));
  h = bf16rn(xs[1]); hv.y = h; lv.y = bf16rn(xs[1] - bf2f(h));
  h = bf16rn(xs[2]); hv.z = h; lv.z = bf16rn(xs[2] - bf2f(h));
  h = bf16rn(xs[3]); hv.w = h; lv.w = bf16rn(xs[3] - bf2f(h));
  ((ushort4*)Enh)[(size_t)row * 256 + t] = hv;
  ((ushort4*)Enl)[(size_t)row * 256 + t] = lv;
}

// ---------------- A0 = relu(En@En^T) via MFMA, 3-term bf16 split; diag=1 ----------------
// Upper-tri tiles, XCD-pinned bi-bands (bi = bid&7 + 8p); grid 640 (pad blocks exit).
__global__ __launch_bounds__(256, 2) void k_syrk_mfma(const ushortT* __restrict__ Enh,
                                                      const ushortT* __restrict__ Enl,
                                                      float* __restrict__ A) {
  int xg = (int)blockIdx.x & 7;
  int j = (int)blockIdx.x >> 3;  // 0..79
  int bi = -1, bj = 0;
#pragma unroll
  for (int p = 0; p < 4; ++p) {
    int bic = xg + (p << 3);
    int c = 32 - bic;
    if (bi < 0) {
      if (j < c) { bi = bic; bj = bic + j; } else j -= c;
    }
  }
  if (bi < 0) return;
  __shared__ ushortT lds[2][16384];  // per buf: A-tile [128][64] @0, B-tile @8192
  int t = threadIdx.x;
  int l = t & 63, w = t >> 6;
  int i0 = bi << 7, j0 = bj << 7;
  int wr = w >> 1, wc = w & 1;
  f32x4 zz = {0.f, 0.f, 0.f, 0.f};
  f32x4 acc[4][4];
#pragma unroll
  for (int m = 0; m < 4; ++m)
#pragma unroll
    for (int n = 0; n < 4; ++n) acc[m][n] = zz;
  int arow_l = l & 15, kslot = l >> 4;

  auto stage = [&](int b, int s) {
    int term = s >> 4;
    int kk0 = (s & 15) << 6;
    const ushortT* sa = (term == 2) ? Enl : Enh;
    const ushortT* sb = (term == 1) ? Enl : Enh;
#pragma unroll
    for (int q = 0; q < 4; ++q) {
      int n = (q << 8) + t;
      int r = n >> 3, p = n & 7;
      int col = (p ^ (r & 7)) << 3;
      gload16(sa + (size_t)(i0 + r) * DD + kk0 + col, &lds[b][n << 3]);
      gload16(sb + (size_t)(j0 + r) * DD + kk0 + col, &lds[b][8192 + (n << 3)]);
    }
  };

  stage(0, 0);
  int cur = 0;
  for (int s = 0; s < 48; ++s) {
    if (s < 47) {
      stage(cur ^ 1, s + 1);
      asm volatile("s_waitcnt vmcnt(8)" ::: "memory");
    } else {
      asm volatile("s_waitcnt vmcnt(0)" ::: "memory");
    }
    __builtin_amdgcn_s_barrier();
#pragma unroll
    for (int kk = 0; kk < 2; ++kk) {
      int g = (kk << 2) + kslot;
      short8 av[4], bv[4];
#pragma unroll
      for (int m = 0; m < 4; ++m) {
        int r = (wr << 6) + (m << 4) + arow_l;
        av[m] = *(const short8*)&lds[cur][(r << 6) + ((g ^ (r & 7)) << 3)];
      }
#pragma unroll
      for (int n = 0; n < 4; ++n) {
        int r = (wc << 6) + (n << 4) + arow_l;
        bv[n] = *(const short8*)&lds[cur][8192 + (r << 6) + ((g ^ (r & 7)) << 3)];
      }
#pragma unroll
      for (int m = 0; m < 4; ++m)
#pragma unroll
        for (int n = 0; n < 4; ++n)
          acc[m][n] = __builtin_amdgcn_mfma_f32_16x16x32_bf16(av[m], bv[n], acc[m][n], 0, 0, 0);
    }
    asm volatile("s_waitcnt lgkmcnt(0)" ::: "memory");
    __builtin_amdgcn_s_barrier();
    cur ^= 1;
  }
  int rbase = (l >> 4) << 2;
#pragma unroll
  for (int m = 0; m < 4; ++m) {
#pragma unroll
    for (int n = 0; n < 4; ++n) {
#pragma unroll
      for (int r = 0; r < 4; ++r) {
        int gi = i0 + (wr << 6) + (m << 4) + rbase + r;
        int gj = j0 + (wc << 6) + (n << 4) + (l & 15);
        float v = fmaxf(acc[m][n][r], 0.0f);
        if (gi == gj) v = 1.0f;
        A[(size_t)gi * NN + gj] = v;
      }
    }
  }
  // mirror via LDS transpose
  if (bi != bj) {
    float* T = (float*)&lds[0][0];
#pragma unroll
    for (int c2 = 0; c2 < 2; ++c2) {
      __syncthreads();
      if (wr == c2) {
#pragma unroll
        for (int m = 0; m < 4; ++m)
#pragma unroll
          for (int n = 0; n < 4; ++n)
#pragma unroll
            for (int r = 0; r < 4; ++r)
              T[(((wc << 6) + (n << 4) + (l & 15)) * 68) + (m << 4) + rbase + r] =
                  fmaxf(acc[m][n][r], 0.0f);
      }
      __syncthreads();
      int lj = t >> 1, cg = (t & 1) << 5;
#pragma unroll
      for (int q = 0; q < 8; ++q) {
        float4 vq = *(const float4*)&T[lj * 68 + cg + (q << 2)];
        *(float4*)&A[(size_t)(j0 + lj) * NN + i0 + (c2 << 6) + cg + (q << 2)] = vq;
      }
    }
  }
}

// ---------------- sigma[i] = 7th largest of row i ----------------
__device__ __forceinline__ void ins7(float (&tv)[7], float v) {
  if (v > tv[6]) {
#pragma unroll
    for (int s = 0; s < 7; s++) {
      if (v > tv[s]) { float tmp = tv[s]; tv[s] = v; v = tmp; }
    }
  }
}
__global__ __launch_bounds__(256) void k_top7(const float* __restrict__ A,
                                              float* __restrict__ sig) {
  int w = threadIdx.x >> 6, lane = threadIdx.x & 63;
  int row = (blockIdx.x << 2) + w;
  const float4* a4 = (const float4*)(A + (size_t)row * NN);
  float tv[7];
#pragma unroll
  for (int i = 0; i < 7; i++) tv[i] = -1.0f;
  for (int k = 0; k < 16; k++) {
    float4 v = a4[(k << 6) + lane];
    ins7(tv, v.x); ins7(tv, v.y); ins7(tv, v.z); ins7(tv, v.w);
  }
  int head = 0;
  float seventh = 0.0f;
  for (int r = 0; r < 7; r++) {
    float h = (head < 7) ? tv[head] : -1.0f;
    float m = h;
#pragma unroll
    for (int off = 32; off; off >>= 1) m = fmaxf(m, __shfl_xor(m, off));
    unsigned long long ball = __ballot(h == m);
    if (lane == (__ffsll(ball) - 1)) head++;
    seventh = m;
  }
  if (lane == 0) sig[row] = seventh;
}

// ---------------- mean pass: sum exp(-(A^2)/(si*sj)) per row, no store ----------------
__global__ __launch_bounds__(256) void k_transform(const float* __restrict__ A,
                                                   const float* __restrict__ sig,
                                                   double* __restrict__ parts) {
  int row = blockIdx.x;
  float si = sig[row];
  const float4* a4 = (const float4*)(A + (size_t)row * NN);
  const float4* s4 = (const float4*)sig;
  int t = threadIdx.x;
  double local = 0.0;
#pragma unroll
  for (int k = 0; k < 4; k++) {
    int j = (k << 8) + t;
    float4 v = a4[j];
    float4 sg = s4[j];
    local += (double)expf(-(v.x * v.x) / (si * sg.x)) +
             (double)expf(-(v.y * v.y) / (si * sg.y)) +
             (double)expf(-(v.z * v.z) / (si * sg.z)) +
             (double)expf(-(v.w * v.w) / (si * sg.w));
  }
  __shared__ double dred[4];
  int lane = t & 63, wv = t >> 6;
#pragma unroll
  for (int off = 32; off; off >>= 1) local += __shfl_xor(local, off);
  if (lane == 0) dred[wv] = local;
  __syncthreads();
  if (t == 0) parts[row] = dred[0] + dred[1] + dred[2] + dred[3];
}

__global__ __launch_bounds__(256) void k_mean(const double* __restrict__ parts,
                                              float* __restrict__ meanb) {
  int t = threadIdx.x;
  double local = 0.0;
#pragma unroll
  for (int k = 0; k < NN / 256; k++) local += parts[(k << 8) + t];
  __shared__ double dred[4];
  int lane = t & 63, wv = t >> 6;
#pragma unroll
  for (int off = 32; off; off >>= 1) local += __shfl_xor(local, off);
  if (lane == 0) dred[wv] = local;
  __syncthreads();
  if (t == 0) meanb[0] = (float)((dred[0] + dred[1] + dred[2] + dred[3]) / ((double)NN * (double)NN));
}

// ---------------- thresh: recompute exp on bottom half, threshold, pack to Ap{L,U} ----
// Fragment-major pack: Ap[rt 128][kc 64][khi 4][arow 16][k0 8] bf16.
__global__ __launch_bounds__(256) void k_thresh_pack(const float* __restrict__ A,
                                                     const float* __restrict__ sig,
                                                     const float* __restrict__ meanb,
                                                     ushortT* __restrict__ ApL,
                                                     ushortT* __restrict__ ApU) {
  float m = meanb[0];
  int i4 = ((int)blockIdx.x << 8) + threadIdx.x;  // 2M over [2048][1024]
  int row2 = i4 >> 10;
  int col4 = (i4 & 1023) << 2;
  int grow = NLAB + row2;
  float si = sig[grow];
  float4 v = *(const float4*)&A[(size_t)grow * NN + col4];
  float4 sg = *(const float4*)&sig[col4];
  float c0 = expf(-(v.x * v.x) / (si * sg.x));
  float c1 = expf(-(v.y * v.y) / (si * sg.y));
  float c2 = expf(-(v.z * v.z) / (si * sg.z));
  float c3 = expf(-(v.w * v.w) / (si * sg.w));
  c0 = (c0 < m) ? 0.0f : c0;
  c1 = (c1 < m) ? 0.0f : c1;
  c2 = (c2 < m) ? 0.0f : c2;
  c3 = (c3 < m) ? 0.0f : c3;
  int half = col4 >> 11;
  int cc = col4 & 2047;
  int rt = row2 >> 4, arow = row2 & 15;
  int kc = cc >> 5, khi = (cc >> 3) & 3, k0 = cc & 7;
  ushortT* dst = half ? ApU : ApL;
  ushort4 hv;
  hv.x = bf16rn(c0); hv.y = bf16rn(c1); hv.z = bf16rn(c2); hv.w = bf16rn(c3);
  *(ushort4*)&dst[((size_t)((rt << 6) + kc) << 9) + (khi << 7) + (arow << 3) + k0] = hv;
}

// ---------------- one-hot labels, packed layout [kc][cf][khi][slot][k0] ----------------
__global__ __launch_bounds__(256) void k_xlabp(const int* __restrict__ labels,
                                               ushortT* __restrict__ Xlabp) {
  int idx = ((int)blockIdx.x << 8) + threadIdx.x;  // 262144
  int c = idx >> 11, j = idx & 2047;
  int kc = j >> 5, khi = (j >> 3) & 3, k0 = j & 7;
  int cf = c >> 4, slot = c & 15;
  Xlabp[((size_t)(((kc << 3) + cf) << 2) + khi) * 128 + (slot << 3) + k0] =
      (labels[j] == c) ? (ushortT)0x3F80 : (ushortT)0;
}

// ---------------- X init: fragment-major Xf f32 + packed Xp bf16 ----------------
__global__ __launch_bounds__(64) void k_xinit(float* __restrict__ Xf,
                                              ushortT* __restrict__ Xp) {
  int rt = blockIdx.x, l = threadIdx.x;
  int col = l & 15, rg4 = l >> 4;
  int kc = rt >> 1;
  int kk = ((rt & 1) << 4) + (rg4 << 2);
  int khi = kk >> 3, k0 = kk & 7;
#pragma unroll
  for (int cf = 0; cf < 8; ++cf) {
    int cls = (cf << 4) + col;
    float v = (cls < NC) ? 0.01f : 0.0f;
    ((f32x4*)Xf)[(size_t)((rt << 3) + cf) * 64 + l] = (f32x4){v, v, v, v};
    ushortT h = bf16rn(v);
    ushort4 hv = {h, h, h, h};
    *(ushort4*)&Xp[((size_t)(((kc << 3) + cf) << 2) + khi) * 128 + (col << 3) + k0] = hv;
  }
}

// ---------------- P: partial GEMM, all loads wave-contiguous 1 KB ----------------
// 512 blocks = 32 rg x 16 s (s pinned to XCD by bid&7); 4 waves; wave = one 16-row
// tile x K=128 slice x 128 classes. Stores C-fragment-major bf16 partials.
__global__ __launch_bounds__(256) void k_gP(const ushortT* __restrict__ Ap,
                                            const ushortT* __restrict__ Xp,
                                            ushortT* __restrict__ Pp) {
  int t = threadIdx.x, l = t & 63, w = t >> 6;
  int bid = (int)blockIdx.x;
  int x = bid & 7, rest = bid >> 3;
  int s = x + ((rest & 1) << 3);  // 0..15
  int rg = rest >> 1;             // 0..31
  int rt = (rg << 2) + w;         // 0..127
  const ushortT* ab = Ap + (((size_t)(rt << 6) + (s << 2)) << 9) + (l << 3);
  const ushortT* xb = Xp + ((size_t)s << 14) + (l << 3);
  short8 av[4];
#pragma unroll
  for (int i = 0; i < 4; ++i) av[i] = *(const short8*)(ab + ((size_t)i << 9));
  f32x4 acc[8];
#pragma unroll
  for (int cf = 0; cf < 8; ++cf) {
    acc[cf] = (f32x4){0.f, 0.f, 0.f, 0.f};
#pragma unroll
    for (int i = 0; i < 4; ++i) {
      short8 bv = *(const short8*)(xb + ((size_t)(i << 3) + cf) * 512);
      acc[cf] = __builtin_amdgcn_mfma_f32_16x16x32_bf16(av[i], bv, acc[cf], 0, 0, 0);
    }
  }
#pragma unroll
  for (int cf = 0; cf < 8; ++cf) {
    ushort4 o;
    o.x = bf16rn(acc[cf][0]); o.y = bf16rn(acc[cf][1]);
    o.z = bf16rn(acc[cf][2]); o.w = bf16rn(acc[cf][3]);
    ((ushort4*)Pp)[((size_t)(((s << 7) + rt) << 3) + cf) * 64 + l] = o;
  }
}

// ---------------- U: reduce 16 partial slices (fragment-major) + fused update ------
// 128 blocks x 64 thr (1 wave per row-tile). All loads/stores coalesced.
template <bool UPDATE>
__global__ __launch_bounds__(64) void k_updU(const ushortT* __restrict__ Pp,
                                             const float* __restrict__ YlabF,
                                             const float* __restrict__ XfPrev,
                                             float* __restrict__ XfOut,
                                             ushortT* __restrict__ XpOut) {
  int rt = blockIdx.x, l = threadIdx.x;
  f32x4 acc[8];
#pragma unroll
  for (int cf = 0; cf < 8; ++cf) acc[cf] = (f32x4){0.f, 0.f, 0.f, 0.f};
  const ushort4* pq = (const ushort4*)Pp;
#pragma unroll
  for (int s = 0; s < 16; ++s) {
#pragma unroll
    for (int cf = 0; cf < 8; ++cf) {
      ushort4 pv = pq[((size_t)(((s << 7) + rt) << 3) + cf) * 64 + l];
      acc[cf][0] += bf2f(pv.x); acc[cf][1] += bf2f(pv.y);
      acc[cf][2] += bf2f(pv.z); acc[cf][3] += bf2f(pv.w);
    }
  }
  if constexpr (!UPDATE) {
#pragma unroll
    for (int cf = 0; cf < 8; ++cf)
      ((f32x4*)XfOut)[(size_t)((rt << 3) + cf) * 64 + l] = acc[cf];
  } else {
    f32x4 mult[8];
    f32x4 rs = {0.f, 0.f, 0.f, 0.f};
#pragma unroll
    for (int cf = 0; cf < 8; ++cf) {
      f32x4 yl = ((const f32x4*)YlabF)[(size_t)((rt << 3) + cf) * 64 + l];
      f32x4 xv = ((const f32x4*)XfPrev)[(size_t)((rt << 3) + cf) * 64 + l];
#pragma unroll
      for (int r = 0; r < 4; ++r) {
        mult[cf][r] = fmaf(xv[r], acc[cf][r] + yl[r], xv[r]);
        rs[r] += mult[cf][r];
      }
    }
#pragma unroll
    for (int msk = 1; msk < 16; msk <<= 1) {
#pragma unroll
      for (int r = 0; r < 4; ++r) rs[r] += __shfl_xor(rs[r], msk);
    }
    f32x4 dn;
#pragma unroll
    for (int r = 0; r < 4; ++r) dn[r] = rs[r] + 1e-8f;
    int col = l & 15, rg4 = l >> 4;
    int kc = rt >> 1;
    int kk = ((rt & 1) << 4) + (rg4 << 2);
    int khi = kk >> 3, k0 = kk & 7;
#pragma unroll
    for (int cf = 0; cf < 8; ++cf) {
      f32x4 ov;
#pragma unroll
      for (int r = 0; r < 4; ++r) ov[r] = mult[cf][r] / dn[r];
      ((f32x4*)XfOut)[(size_t)((rt << 3) + cf) * 64 + l] = ov;
      ushort4 xo;
      xo.x = bf16rn(ov[0]); xo.y = bf16rn(ov[1]);
      xo.z = bf16rn(ov[2]); xo.w = bf16rn(ov[3]);
      *(ushort4*)&XpOut[((size_t)(((kc << 3) + cf) << 2) + khi) * 128 + (col << 3) + k0] = xo;
    }
  }
}

// ---------------- output assembly (reads fragment-major Xf) ----------------
__global__ __launch_bounds__(256) void k_output(const float* __restrict__ Xf,
                                                const int* __restrict__ labels,
                                                float* __restrict__ out) {
  int idx = ((int)blockIdx.x << 8) + threadIdx.x;  // 409600
  int i = idx / NC, c = idx - i * NC;
  float v;
  if (i < NLAB) {
    v = (labels[i] == c) ? 1.0f : 0.0f;
  } else {
    int row = i - NLAB;
    int rt = row >> 4, r = row & 15;
    int rg4 = r >> 2, reg = r & 3;
    int cf = c >> 4, col = c & 15;
    v = Xf[((size_t)(((rt << 3) + cf) << 6) + (rg4 << 4) + col) * 4 + reg];
  }
  out[idx] = v;
}

extern "C" void kernel_launch(void* const* d_in, const int* in_sizes, int n_in,
                              void* d_out, int out_size, void* d_ws, size_t ws_size,
                              hipStream_t stream) {
  const float* E = (const float*)d_in[0];
  const int* labels = (const int*)d_in[1];
  float* out = (float*)d_out;
  char* ws = (char*)d_ws;
  const size_t MB = 1024 * 1024;

  float* A = (float*)ws;                          // 64 MB
  ushortT* Enh = (ushortT*)(ws + 64 * MB);        // 8 MB
  ushortT* Enl = (ushortT*)(ws + 72 * MB);        // 8 MB
  ushortT* ApL = (ushortT*)(ws + 80 * MB);        // 8 MB packed A[:, :2048]
  ushortT* ApU = (ushortT*)(ws + 88 * MB);        // 8 MB packed A[:, 2048:]
  float* sig = (float*)(ws + 96 * MB);
  double* parts = (double*)(ws + 96 * MB + 65536);
  float* meanb = (float*)(ws + 96 * MB + 131072);
  ushortT* Xlabp = (ushortT*)(ws + 97 * MB);      // 0.5 MB packed
  float* YlabF = (float*)(ws + 98 * MB);          // 1 MB frag-major
  float* Xf0 = (float*)(ws + 99 * MB);            // 1 MB frag-major
  float* Xf1 = (float*)(ws + 100 * MB);           // 1 MB
  ushortT* Xp0 = (ushortT*)(ws + 101 * MB);       // 0.5 MB packed
  ushortT* Xp1 = (ushortT*)(ws + 102 * MB);       // 0.5 MB
  ushortT* Pp = (ushortT*)(ws + 104 * MB);        // 8 MB partials frag-major

  k_normalize<<<NN, 256, 0, stream>>>(E, Enh, Enl);
  k_syrk_mfma<<<640, 256, 0, stream>>>(Enh, Enl, A);
  k_top7<<<NN / 4, 256, 0, stream>>>(A, sig);
  k_transform<<<NN, 256, 0, stream>>>(A, sig, parts);
  k_mean<<<1, 256, 0, stream>>>(parts, meanb);
  k_thresh_pack<<<8192, 256, 0, stream>>>(A, sig, meanb, ApL, ApU);
  k_xlabp<<<1024, 256, 0, stream>>>(labels, Xlabp);
  k_xinit<<<128, 64, 0, stream>>>(Xf0, Xp0);
  // Ylab = A[unlab, :2048] @ onehot  (P on ApL/Xlabp, U<false> -> YlabF)
  k_gP<<<512, 256, 0, stream>>>(ApL, Xlabp, Pp);
  k_updU<false><<<128, 64, 0, stream>>>(Pp, nullptr, nullptr, YlabF, nullptr);
  float* xf[2] = {Xf0, Xf1};
  ushortT* xp[2] = {Xp0, Xp1};
  int cur = 0;
  for (int it = 0; it < NITER; ++it) {
    int nxt = cur ^ 1;
    k_gP<<<512, 256, 0, stream>>>(ApU, xp[cur], Pp);
    k_updU<true><<<128, 64, 0, stream>>>(Pp, YlabF, xf[cur], xf[nxt], xp[nxt]);
    cur = nxt;
  }
  k_output<<<1600, 256, 0, stream>>>(xf[cur], labels, out);
}